// Round 11
// baseline (427.534 us; speedup 1.0000x reference)
//
#include <hip/hip_runtime.h>
#include <hip/hip_bf16.h>

// ---------- types ----------
using short8 = __attribute__((ext_vector_type(8))) short;
using f32x4  = __attribute__((ext_vector_type(4))) float;

// f32 -> bf16 round-to-nearest-even
__device__ __forceinline__ unsigned short f2bf(float f) {
    union { float f; unsigned u; } x; x.f = f;
    unsigned r = x.u + 0x7FFFu + ((x.u >> 16) & 1u);
    return (unsigned short)(r >> 16);
}

// async global->LDS, 16B per lane; lds base must be wave-uniform
__device__ __forceinline__ void gload_lds16(const void* g, void* l) {
    __builtin_amdgcn_global_load_lds(
        (const __attribute__((address_space(1))) unsigned int*)g,
        (__attribute__((address_space(3))) unsigned int*)l, 16, 0, 0);
}

// ---------- mask dtype detector ----------
__global__ void detect_mask_kernel(const unsigned int* __restrict__ m, int* __restrict__ flag) {
    if (threadIdx.x == 0) *flag = 0;
    __syncthreads();
    unsigned v = m[threadIdx.x];
    if (v > 1u) {
        atomicOr(flag, 1);
        if (v != 0x3F800000u) atomicOr(flag, 2);
    }
}

// ---------- pack mask into bitmask (grid-stride) ----------
__global__ __launch_bounds__(256) void maskpack_kernel(
    const void* __restrict__ mask, const int* __restrict__ flag,
    unsigned long long* __restrict__ Mb, int nwords)
{
    const int l = threadIdx.x & 63;
    const int gwave = (int)((blockIdx.x * 256 + threadIdx.x) >> 6);
    const int nw = (int)((gridDim.x * 256) >> 6);
    const bool bytem = ((*flag) & 2) != 0;
    const unsigned char* m8 = (const unsigned char*)mask;
    const unsigned int* m32 = (const unsigned int*)mask;
    for (int w0 = gwave * 4; w0 < nwords; w0 += nw * 4) {
        unsigned v[4];
#pragma unroll
        for (int u = 0; u < 4; u++) {
            size_t e = (size_t)(w0 + u) * 64 + l;
            v[u] = bytem ? (unsigned)m8[e] : m32[e];
        }
#pragma unroll
        for (int u = 0; u < 4; u++) {
            unsigned long long b = __ballot(v[u] != 0u);
            if (l == 0) Mb[w0 + u] = b;
        }
    }
}

// ---------- transpose-convert W (f32 [k][n]) -> Wt (bf16 [n][k]) ----------
__global__ __launch_bounds__(256) void wconv_kernel(
    const float* __restrict__ W0, const float* __restrict__ W1,
    const float* __restrict__ W2, const float* __restrict__ W3,
    unsigned short* __restrict__ Wt)
{
    const int z = blockIdx.z;
    const float* W = (z == 0) ? W0 : ((z == 1) ? W1 : ((z == 2) ? W2 : W3));
    unsigned short* O = Wt + (size_t)z * 1024 * 1024;
    __shared__ float tile[64][68];
    const int t = threadIdx.x;
    const int k0 = blockIdx.x * 64, n0 = blockIdx.y * 64;
    const int rr = t >> 4, cc = t & 15;
#pragma unroll
    for (int i = 0; i < 4; i++) {
        int row = rr + i * 16;
        float4 v = *reinterpret_cast<const float4*>(W + (size_t)(k0 + row) * 1024 + n0 + cc * 4);
        *reinterpret_cast<float4*>(&tile[row][cc * 4]) = v;
    }
    __syncthreads();
#pragma unroll
    for (int i = 0; i < 4; i++) {
        int rn = rr + i * 16;
        ushort4 ov;
        ov.x = f2bf(tile[cc * 4 + 0][rn]);
        ov.y = f2bf(tile[cc * 4 + 1][rn]);
        ov.z = f2bf(tile[cc * 4 + 2][rn]);
        ov.w = f2bf(tile[cc * 4 + 3][rn]);
        *reinterpret_cast<ushort4*>(O + (size_t)(n0 + rn) * 1024 + k0 + cc * 4) = ov;
    }
}

// ---------- convert f32 A -> bf16 A ----------
__global__ __launch_bounds__(256) void aconv_kernel(
    const float* __restrict__ Aq, const float* __restrict__ Ak, const float* __restrict__ Av,
    unsigned short* __restrict__ Out)
{
    const int z = blockIdx.y;
    const float* A = (z == 0) ? Aq : ((z == 1) ? Ak : Av);
    unsigned short* O = Out + (size_t)z * 8192 * 1024;
    size_t i = ((size_t)blockIdx.x * 256 + threadIdx.x) * 8;
    float4 v0 = *reinterpret_cast<const float4*>(A + i);
    float4 v1 = *reinterpret_cast<const float4*>(A + i + 4);
    short8 o;
    o[0] = (short)f2bf(v0.x); o[1] = (short)f2bf(v0.y);
    o[2] = (short)f2bf(v0.z); o[3] = (short)f2bf(v0.w);
    o[4] = (short)f2bf(v1.x); o[5] = (short)f2bf(v1.y);
    o[6] = (short)f2bf(v1.z); o[7] = (short)f2bf(v1.w);
    *reinterpret_cast<short8*>(O + i) = o;
}

// ---------- 8-phase 256x256 BK=64 projection GEMM (T2+T3+T5), dyn LDS 128KB ----------
// A [8192][1024] bf16 row-major, W [1024 n][1024 k] bf16; 512 thr = 8 waves (2M x 4N).
// LDS: Abuf[2] @0/32768 ([256 rows][128B], st_16x32 swizzled), Bbuf[2] @65536/98304.
__global__ __launch_bounds__(512, 2) void gemm_proj8_kernel(
    const unsigned short* __restrict__ Abf,  // [3][8192][1024]
    const unsigned short* __restrict__ Wt,   // [3][1024 n][1024 k]
    const float* __restrict__ bq, const float* __restrict__ bk, const float* __restrict__ bv,
    unsigned short* __restrict__ Out)        // [3][8][16][1024][64]
{
    extern __shared__ char smem[];
    const int z = blockIdx.z;
    const unsigned short* A = Abf + (size_t)z * 8192 * 1024;
    const unsigned short* Wz = Wt + (size_t)z * 1024 * 1024;
    const float* bias = (z == 0) ? bq : ((z == 1) ? bk : bv);
    unsigned short* Oz = Out + (size_t)z * 8 * 16 * 1024 * 64;

    const int tid = threadIdx.x, w = tid >> 6, l = tid & 63, l16 = l & 15, g = l >> 4;
    const int wm = w >> 2, wn = w & 3;
    const int row0 = blockIdx.x * 256, col0 = blockIdx.y * 256;

    // staging: half-tile = 128 rows x 128B = 16KB; per wave 2 GLL x 1KB slices.
    // dest linear; source col pre-swizzled (st_16x32: byte ^= ((byte>>9)&1)<<5
    // => per-lane csrc = (l&7)*16 ^ ((l>>5)<<5), row_local = w*16 + j*8 + (l>>3)).
    const int csrc = ((l & 7) * 16) ^ ((l >> 5) << 5);
    const char* gA = (const char*)A + (size_t)(row0 + w * 16 + (l >> 3)) * 2048 + csrc;
    const char* gB = (const char*)Wz + (size_t)(col0 + w * 16 + (l >> 3)) * 2048 + csrc;
    // j=1 adds 8 rows = 16384 bytes global; half h adds 128 rows = 262144 bytes.

    // swizzled ds_read offsets: row = (wm*128|wn*64) + f*16 + l16; sw = ((l16>>2)&1)<<5
    const int sw = ((l16 >> 2) & 1) << 5;
    const int ard = (wm * 128 + l16) * 128 + ((g * 16) ^ sw);   // + mh*8192 + mf*2048 + kk*64
    const int brd = (wn * 64 + l16) * 128 + ((g * 16) ^ sw);    // + nf*2048 + kk*64

    f32x4 acc[8][4];
#pragma unroll
    for (int i = 0; i < 8; i++)
#pragma unroll
        for (int j = 0; j < 4; j++) acc[i][j] = (f32x4){0.f, 0.f, 0.f, 0.f};

    // prologue: stage all 4 half-tiles of K-tile 0 into buf0; drain; barrier
#pragma unroll
    for (int h = 0; h < 2; h++) {
        gload_lds16(gA + h * 262144, smem + h * 16384 + w * 2048);
        gload_lds16(gA + h * 262144 + 16384, smem + h * 16384 + w * 2048 + 1024);
        gload_lds16(gB + h * 262144, smem + 65536 + h * 16384 + w * 2048);
        gload_lds16(gB + h * 262144 + 16384, smem + 65536 + h * 16384 + w * 2048 + 1024);
    }
    asm volatile("s_waitcnt vmcnt(0)" ::: "memory");
    __builtin_amdgcn_s_barrier();
    __builtin_amdgcn_sched_barrier(0);

    for (int t = 0; t < 16; t++) {
        const int buf = (t & 1) * 32768, nbuf = 32768 - buf;
        const int dost = (t < 15);
        const size_t knext = (size_t)(t + 1) * 128;
#pragma unroll
        for (int p = 0; p < 4; p++) {
            const int kk = p & 1, mh = p >> 1;
            // ds-read this phase's fragments (current buf, fully staged)
            short8 a[4], bm[4];
#pragma unroll
            for (int mf = 0; mf < 4; mf++)
                a[mf] = *reinterpret_cast<const short8*>(
                    smem + buf + ard + mh * 8192 + mf * 2048 + kk * 64);
#pragma unroll
            for (int nf = 0; nf < 4; nf++)
                bm[nf] = *reinterpret_cast<const short8*>(
                    smem + 65536 + buf + brd + nf * 2048 + kk * 64);
            // stage half-tile p of K-tile t+1 into nbuf
            if (dost) {
                if (p < 2) {
                    gload_lds16(gA + p * 262144 + knext, smem + nbuf + p * 16384 + w * 2048);
                    gload_lds16(gA + p * 262144 + 16384 + knext, smem + nbuf + p * 16384 + w * 2048 + 1024);
                } else {
                    gload_lds16(gB + (p - 2) * 262144 + knext, smem + 65536 + nbuf + (p - 2) * 16384 + w * 2048);
                    gload_lds16(gB + (p - 2) * 262144 + 16384 + knext, smem + 65536 + nbuf + (p - 2) * 16384 + w * 2048 + 1024);
                }
            }
            __builtin_amdgcn_s_barrier();
            asm volatile("s_waitcnt lgkmcnt(0)" ::: "memory");
            __builtin_amdgcn_sched_barrier(0);
            __builtin_amdgcn_s_setprio(1);
#pragma unroll
            for (int mf = 0; mf < 4; mf++)
#pragma unroll
                for (int nf = 0; nf < 4; nf++)
                    acc[mh * 4 + mf][nf] = __builtin_amdgcn_mfma_f32_16x16x32_bf16(
                        a[mf], bm[nf], acc[mh * 4 + mf][nf], 0, 0, 0);
            __builtin_amdgcn_s_setprio(0);
            if (p == 3) asm volatile("s_waitcnt vmcnt(0)" ::: "memory");
            __builtin_amdgcn_s_barrier();
            __builtin_amdgcn_sched_barrier(0);
        }
    }

    // epilogue: bias + reshape -> [b][h][n][64] bf16
#pragma unroll
    for (int mf8 = 0; mf8 < 8; mf8++)
#pragma unroll
        for (int nf = 0; nf < 4; nf++)
#pragma unroll
            for (int r = 0; r < 4; r++) {
                int row = row0 + wm * 128 + mf8 * 16 + g * 4 + r;
                int col = col0 + wn * 64 + nf * 16 + l16;
                float val = acc[mf8][nf][r] + bias[col];
                int bb = row >> 10, n = row & 1023;
                int h = col >> 6, d = col & 63;
                Oz[(((size_t)(bb * 16 + h)) * 1024 + n) * 64 + d] = f2bf(val);
            }
}

// ---------- 128x128 GEMM core, 3-buf LDS, stage lead-2, counted vmcnt(4) ----------
#define GEMM_IT(KT, RB, SB, DOST, WN)                                                       \
    {                                                                                       \
        if (DOST) {                                                                         \
            const int ko = ((KT) + 2) * 64;                                                 \
            gload_lds16(gA0 + ko, lA0_##SB); gload_lds16(gA1 + ko, lA1_##SB);               \
            gload_lds16(gB0 + ko, lB0_##SB); gload_lds16(gB1 + ko, lB1_##SB);               \
        }                                                                                   \
        short8 af[4], bfm[4];                                                               \
        _Pragma("unroll")                                                                   \
        for (int fr = 0; fr < 4; fr++)                                                      \
            af[fr] = *reinterpret_cast<const short8*>(rdA + (RB) * 8192 + fr * 1024);       \
        _Pragma("unroll")                                                                   \
        for (int fc = 0; fc < 4; fc++)                                                      \
            bfm[fc] = *reinterpret_cast<const short8*>(rdB + (RB) * 8192 + fc * 1024);      \
        _Pragma("unroll")                                                                   \
        for (int fr = 0; fr < 4; fr++)                                                      \
            _Pragma("unroll")                                                               \
            for (int fc = 0; fc < 4; fc++)                                                  \
                acc[fr][fc] = __builtin_amdgcn_mfma_f32_16x16x32_bf16(af[fr], bfm[fc], acc[fr][fc], 0, 0, 0); \
        asm volatile("s_waitcnt vmcnt(" #WN ")" ::: "memory");                              \
        __builtin_amdgcn_s_barrier();                                                       \
        __builtin_amdgcn_sched_barrier(0);                                                  \
    }

#define GEMM_IT_LAST(RB)                                                                    \
    {                                                                                       \
        short8 af[4], bfm[4];                                                               \
        _Pragma("unroll")                                                                   \
        for (int fr = 0; fr < 4; fr++)                                                      \
            af[fr] = *reinterpret_cast<const short8*>(rdA + (RB) * 8192 + fr * 1024);       \
        _Pragma("unroll")                                                                   \
        for (int fc = 0; fc < 4; fc++)                                                      \
            bfm[fc] = *reinterpret_cast<const short8*>(rdB + (RB) * 8192 + fc * 1024);      \
        _Pragma("unroll")                                                                   \
        for (int fr = 0; fr < 4; fr++)                                                      \
            _Pragma("unroll")                                                               \
            for (int fc = 0; fc < 4; fc++)                                                  \
                acc[fr][fc] = __builtin_amdgcn_mfma_f32_16x16x32_bf16(af[fr], bfm[fc], acc[fr][fc], 0, 0, 0); \
    }

#define GEMM_CORE(A_PTR, W_PTR)                                                             \
    __shared__ unsigned short Ab[3][4096];                                                  \
    __shared__ unsigned short Bb[3][4096];                                                  \
    const int tid = threadIdx.x, w = tid >> 6, l = tid & 63, l16 = l & 15, g = l >> 4;      \
    const int wr = w >> 1, wc = w & 1;                                                      \
    const int row0 = blockIdx.x * 128, col0 = blockIdx.y * 128;                             \
    const int offs = tid * 16;                                                              \
    const char* gA0 = (const char*)(A_PTR) + (size_t)(row0 + (offs >> 6)) * 2048 + (offs & 63);          \
    const char* gA1 = (const char*)(A_PTR) + (size_t)(row0 + ((offs + 4096) >> 6)) * 2048 + (offs & 63); \
    const char* gB0 = (const char*)(W_PTR) + (size_t)(col0 + (offs >> 6)) * 2048 + (offs & 63);          \
    const char* gB1 = (const char*)(W_PTR) + (size_t)(col0 + ((offs + 4096) >> 6)) * 2048 + (offs & 63); \
    char* lA0_0 = (char*)Ab[0] + w * 1024; char* lA1_0 = (char*)Ab[0] + 4096 + w * 1024;    \
    char* lA0_1 = (char*)Ab[1] + w * 1024; char* lA1_1 = (char*)Ab[1] + 4096 + w * 1024;    \
    char* lA0_2 = (char*)Ab[2] + w * 1024; char* lA1_2 = (char*)Ab[2] + 4096 + w * 1024;    \
    char* lB0_0 = (char*)Bb[0] + w * 1024; char* lB1_0 = (char*)Bb[0] + 4096 + w * 1024;    \
    char* lB0_1 = (char*)Bb[1] + w * 1024; char* lB1_1 = (char*)Bb[1] + 4096 + w * 1024;    \
    char* lB0_2 = (char*)Bb[2] + w * 1024; char* lB1_2 = (char*)Bb[2] + 4096 + w * 1024;    \
    const char* rdA = (char*)Ab[0] + (wr * 64 + l16) * 64 + g * 16;                         \
    const char* rdB = (char*)Bb[0] + (wc * 64 + l16) * 64 + g * 16;                         \
    f32x4 acc[4][4];                                                                        \
    _Pragma("unroll")                                                                       \
    for (int i = 0; i < 4; i++)                                                             \
        _Pragma("unroll")                                                                   \
        for (int j = 0; j < 4; j++) acc[i][j] = (f32x4){0.f, 0.f, 0.f, 0.f};                \
    gload_lds16(gA0, lA0_0); gload_lds16(gA1, lA1_0);                                       \
    gload_lds16(gB0, lB0_0); gload_lds16(gB1, lB1_0);                                       \
    gload_lds16(gA0 + 64, lA0_1); gload_lds16(gA1 + 64, lA1_1);                             \
    gload_lds16(gB0 + 64, lB0_1); gload_lds16(gB1 + 64, lB1_1);                             \
    asm volatile("s_waitcnt vmcnt(4)" ::: "memory");                                        \
    __builtin_amdgcn_s_barrier();                                                           \
    __builtin_amdgcn_sched_barrier(0);                                                      \
    for (int kt0 = 0; kt0 < 30; kt0 += 3) {                                                 \
        GEMM_IT(kt0 + 0, 0, 2, 1, 4)                                                        \
        GEMM_IT(kt0 + 1, 1, 0, 1, 4)                                                        \
        GEMM_IT(kt0 + 2, 2, 1, 1, 4)                                                        \
    }                                                                                       \
    GEMM_IT(30, 0, 0, 0, 0)                                                                 \
    GEMM_IT_LAST(1)

// ---------- output projection: d_out = AO @ Wo^T + bo (f32 out) ----------
__global__ __launch_bounds__(256, 3) void gemm_out_kernel(
    const unsigned short* __restrict__ Ain,
    const unsigned short* __restrict__ Wto,
    const float* __restrict__ bo,
    float* __restrict__ Out)
{
    GEMM_CORE(Ain, Wto)

#pragma unroll
    for (int fr = 0; fr < 4; fr++)
#pragma unroll
        for (int fc = 0; fc < 4; fc++)
#pragma unroll
            for (int r = 0; r < 4; r++) {
                int row = row0 + wr * 64 + fr * 16 + g * 4 + r;
                int col = col0 + wc * 64 + fc * 16 + l16;
                Out[(size_t)row * 1024 + col] = acc[fr][fc][r] + bo[col];
            }
}

// ---------- projection GEMM (f32 A fallback, converts in-loop) ----------
__global__ __launch_bounds__(256) void proj_f32_kernel(
    const float* __restrict__ Aq, const float* __restrict__ Ak, const float* __restrict__ Av,
    const unsigned short* __restrict__ Wt,
    const float* __restrict__ bq, const float* __restrict__ bk, const float* __restrict__ bv,
    unsigned short* __restrict__ Out)
{
    const int z = blockIdx.z;
    const float* A = (z == 0) ? Aq : ((z == 1) ? Ak : Av);
    const float* bias = (z == 0) ? bq : ((z == 1) ? bk : bv);
    const unsigned short* Wz = Wt + (size_t)z * 1024 * 1024;
    unsigned short* Oz = Out + (size_t)z * 8 * 16 * 1024 * 64;

    const int tid = threadIdx.x;
    const int w = tid >> 6, l = tid & 63;
    const int l16 = l & 15, g = l >> 4;
    const int rbase = blockIdx.x * 128 + w * 32;
    const int cbase = blockIdx.y * 64;

    f32x4 acc[2][4];
#pragma unroll
    for (int i = 0; i < 2; i++)
#pragma unroll
        for (int j = 0; j < 4; j++) acc[i][j] = (f32x4){0.f, 0.f, 0.f, 0.f};

#pragma unroll 2
    for (int k0 = 0; k0 < 1024; k0 += 32) {
        short8 a[2];
#pragma unroll
        for (int rf = 0; rf < 2; rf++) {
            const float* ap = A + (size_t)(rbase + rf * 16 + l16) * 1024 + k0 + g * 8;
            float4 v0 = *reinterpret_cast<const float4*>(ap);
            float4 v1 = *reinterpret_cast<const float4*>(ap + 4);
            short8 av;
            av[0] = (short)f2bf(v0.x); av[1] = (short)f2bf(v0.y);
            av[2] = (short)f2bf(v0.z); av[3] = (short)f2bf(v0.w);
            av[4] = (short)f2bf(v1.x); av[5] = (short)f2bf(v1.y);
            av[6] = (short)f2bf(v1.z); av[7] = (short)f2bf(v1.w);
            a[rf] = av;
        }
        short8 bfr[4];
#pragma unroll
        for (int cf = 0; cf < 4; cf++)
            bfr[cf] = *reinterpret_cast<const short8*>(Wz + (size_t)(cbase + cf * 16 + l16) * 1024 + k0 + g * 8);
#pragma unroll
        for (int rf = 0; rf < 2; rf++)
#pragma unroll
            for (int cf = 0; cf < 4; cf++)
                acc[rf][cf] = __builtin_amdgcn_mfma_f32_16x16x32_bf16(a[rf], bfr[cf], acc[rf][cf], 0, 0, 0);
    }

#pragma unroll
    for (int rf = 0; rf < 2; rf++)
#pragma unroll
        for (int cf = 0; cf < 4; cf++)
#pragma unroll
            for (int r = 0; r < 4; r++) {
                int row = rbase + rf * 16 + g * 4 + r;
                int col = cbase + cf * 16 + l16;
                float val = acc[rf][cf][r] + bias[col];
                int bb = row >> 10, n = row & 1023;
                int h = col >> 6, d = col & 63;
                Oz[(((size_t)(bb * 16 + h)) * 1024 + n) * 64 + d] = f2bf(val);
            }
}

// ---------- transpose V: Vs [bh][k][64 d] -> Vt [bh][64 d][1024 k] ----------
__global__ __launch_bounds__(256) void vtrans_kernel(
    const unsigned short* __restrict__ Vs, unsigned short* __restrict__ Vt)
{
    const int bh = blockIdx.y;
    const int k0 = blockIdx.x * 64;
    const unsigned short* In = Vs + (size_t)bh * 1024 * 64;
    unsigned short* O = Vt + (size_t)bh * 64 * 1024;
    __shared__ unsigned short tile[64][72];
    const int t = threadIdx.x;
    {
        const int row = t >> 3;
        const int c8 = (t & 7) * 8;
#pragma unroll
        for (int i = 0; i < 2; i++) {
            int r = row + i * 32;
            short8 v = *reinterpret_cast<const short8*>(In + (size_t)(k0 + r) * 64 + c8);
            *reinterpret_cast<short8*>(&tile[r][c8]) = v;
        }
    }
    __syncthreads();
    {
        const int rd = t >> 4, c4 = (t & 15) * 4;
#pragma unroll
        for (int i = 0; i < 4; i++) {
            int d = rd + i * 16;
            ushort4 ov;
            ov.x = tile[c4 + 0][d];
            ov.y = tile[c4 + 1][d];
            ov.z = tile[c4 + 2][d];
            ov.w = tile[c4 + 3][d];
            *reinterpret_cast<ushort4*>(O + (size_t)d * 1024 + k0 + c4) = ov;
        }
    }
}

// ---------- fused attention, KVBLK=128 (unchanged from round 10) ----------
__global__ __launch_bounds__(512, 1) void attn_kernel(
    const unsigned short* __restrict__ Qs,     // [bh][1024][64]
    const unsigned short* __restrict__ Ks,     // [bh][1024][64]
    const unsigned short* __restrict__ Vt,     // [bh][64 d][1024 k]
    const float* __restrict__ attw,            // [bh][1024][1024]
    const unsigned long long* __restrict__ Mb, // [bh*1024 rows][16 words]
    unsigned short* __restrict__ AO)           // [b][q][h*64+d] bf16
{
    extern __shared__ char smem[];

    const int bid = blockIdx.x;
    const int xj = bid & 7, xp = bid >> 3;
    const int qt = xp & 7;
    const int gbh = (xp >> 3) * 8 + xj;
    const int h = gbh & 15, b = gbh >> 4;
    const int bh = b * 16 + h;

    const int tid = threadIdx.x, w = tid >> 6, l = tid & 63, l16 = l & 15, g = l >> 4;
    const int myq = qt * 128 + w * 16 + l16;

    const unsigned short* Qbh = Qs + (size_t)bh * 65536;
    const char* Kb = (const char*)(Ks + (size_t)bh * 65536);
    const char* Vb = (const char*)(Vt + (size_t)bh * 65536);
    const float* wrow = attw + ((size_t)bh * 1024 + myq) * 1024;
    const unsigned long long* mrow = Mb + ((size_t)bh * 1024 + myq) * 16;

    const int kb_swz = ((l & 7) * 16) ^ ((l >> 3) << 4);
    const char* gKb = Kb + (size_t)(w * 16 + (l >> 3)) * 128 + kb_swz;
    const int vrow0 = w * 8 + (l >> 4);
    const char* gVb0 = Vb + (size_t)vrow0 * 2048 + (((l & 15) * 16) ^ ((vrow0 & 7) << 4));
    const char* gVb1 = Vb + (size_t)(vrow0 + 4) * 2048 + (((l & 15) * 16) ^ (((vrow0 + 4) & 7) << 4));

    const int swz = (l16 & 7) << 4;
    const int krdA = l16 * 128 + ((g * 16) ^ swz);
    const int krdB = l16 * 128 + ((64 + g * 16) ^ swz);
    char* const pbase = smem + 65536 + w * 4096 + l16 * 256;

    gload_lds16(gKb, smem + w * 2048);
    gload_lds16(gKb + 1024, smem + w * 2048 + 1024);
    gload_lds16(gVb0, smem + 32768 + w * 2048);
    gload_lds16(gVb1, smem + 32768 + w * 2048 + 1024);
    __builtin_amdgcn_sched_barrier(0);

    short8 qf0 = *reinterpret_cast<const short8*>(Qbh + (size_t)myq * 64 + g * 8);
    short8 qf1 = *reinterpret_cast<const short8*>(Qbh + (size_t)myq * 64 + 32 + g * 8);
    float4 wv[8];
    unsigned long long mb0, mb1;
#pragma unroll
    for (int cf = 0; cf < 8; cf++)
        wv[cf] = *reinterpret_cast<const float4*>(wrow + cf * 16 + g * 4);
    mb0 = mrow[0];
    mb1 = mrow[1];

    asm volatile("s_waitcnt vmcnt(12)" ::: "memory");
    __builtin_amdgcn_s_barrier();
    __builtin_amdgcn_sched_barrier(0);

    f32x4 accO[4];
#pragma unroll
    for (int j = 0; j < 4; j++) accO[j] = (f32x4){0.f, 0.f, 0.f, 0.f};
    float den = 0.f;

#define ATTN_BODY(CURK)                                                                     \
    _Pragma("unroll")                                                                       \
    for (int cf = 0; cf < 8; cf++) {                                                        \
        short8 k0 = *reinterpret_cast<const short8*>(smem + (CURK) + krdA + cf * 2048);     \
        short8 k1 = *reinterpret_cast<const short8*>(smem + (CURK) + krdB + cf * 2048);     \
        f32x4 s = (f32x4){0.f, 0.f, 0.f, 0.f};                                              \
        s = __builtin_amdgcn_mfma_f32_16x16x32_bf16(k0, qf0, s, 0, 0, 0);                   \
        s = __builtin_amdgcn_mfma_f32_16x16x32_bf16(k1, qf1, s, 0, 0, 0);                   \
        unsigned mn = (unsigned)((cf < 4 ? mb0 >> (cf * 16 + g * 4)                         \
                                         : mb1 >> ((cf - 4) * 16 + g * 4))) & 0xFu;         \
        float p0 = (mn & 1u) ? 0.f : __expf(s[0] * 0.125f * wv[cf].x);                      \
        float p1 = (mn & 2u) ? 0.f : __expf(s[1] * 0.125f * wv[cf].y);                      \
        float p2 = (mn & 4u) ? 0.f : __expf(s[2] * 0.125f * wv[cf].z);                      \
        float p3 = (mn & 8u) ? 0.f : __expf(s[3] * 0.125f * wv[cf].w);                      \
        den += p0 + p1 + p2 + p3;                                                           \
        ushort4 pwv;                                                                        \
        pwv.x = f2bf(p0); pwv.y = f2bf(p1); pwv.z = f2bf(p2); pwv.w = f2bf(p3);             \
        *reinterpret_cast<ushort4*>(pbase + ((cf * 32 + g * 8) ^ swz)) = pwv;               \
    }

#define ATTN_PV(CURV)                                                                       \
    _Pragma("unroll")                                                                       \
    for (int ks = 0; ks < 4; ks++) {                                                        \
        short8 pf = *reinterpret_cast<const short8*>(pbase + ((ks * 64 + g * 16) ^ swz));   \
        _Pragma("unroll")                                                                   \
        for (int cd = 0; cd < 4; cd++) {                                                    \
            short8 vf = *reinterpret_cast<const short8*>(                                   \
                smem + 32768 + (CURV) + (cd * 16 + l16) * 256 + ((ks * 64 + g * 16) ^ swz));\
            accO[cd] = __builtin_amdgcn_mfma_f32_16x16x32_bf16(pf, vf, accO[cd], 0, 0, 0);  \
        }                                                                                   \
    }

    for (int t = 0; t < 7; t++) {
        const int cur = (t & 1) * 16384, nxt = 16384 - cur;
        gload_lds16(gKb + (size_t)(t + 1) * 16384, smem + nxt + w * 2048);
        gload_lds16(gKb + (size_t)(t + 1) * 16384 + 1024, smem + nxt + w * 2048 + 1024);
        gload_lds16(gVb0 + (size_t)(t + 1) * 256, smem + 32768 + nxt + w * 2048);
        gload_lds16(gVb1 + (size_t)(t + 1) * 256, smem + 32768 + nxt + w * 2048 + 1024);
        __builtin_amdgcn_sched_barrier(0);

        ATTN_BODY(cur)

#pragma unroll
        for (int cf = 0; cf < 8; cf++)
            wv[cf] = *reinterpret_cast<const float4*>(wrow + (t + 1) * 128 + cf * 16 + g * 4);
        mb0 = mrow[2 * (t + 1)];
        mb1 = mrow[2 * (t + 1) + 1];

        ATTN_PV(cur)

        asm volatile("s_waitcnt vmcnt(10)" ::: "memory");
        __builtin_amdgcn_s_barrier();
        __builtin_amdgcn_sched_barrier(0);
    }
    ATTN_BODY(16384)
    ATTN_PV(16384)
#undef ATTN_BODY
#undef ATTN_PV

    den += __shfl_xor(den, 16);
    den += __shfl_xor(den, 32);

#pragma unroll
    for (int r = 0; r < 4; r++) {
        float dr = __shfl(den, g * 4 + r);
        float inv = 1.0f / dr;
#pragma unroll
        for (int cd = 0; cd < 4; cd++) {
            int qrow = qt * 128 + w * 16 + g * 4 + r;
            int col = h * 64 + cd * 16 + l16;
            AO[((size_t)b * 1024 + qrow) * 1024 + col] = f2bf(accO[cd][r] * inv);
        }
    }
}

extern "C" void kernel_launch(void* const* d_in, const int* in_sizes, int n_in,
                              void* d_out, int out_size, void* d_ws, size_t ws_size,
                              hipStream_t stream)
{
    const float* queries = (const float*)d_in[0];
    const float* keys    = (const float*)d_in[1];
    const float* values  = (const float*)d_in[2];
    const void*  mask    = d_in[3];
    const float* attw    = (const float*)d_in[4];
    const float* Wq = (const float*)d_in[5];
    const float* bq = (const float*)d_in[6];
    const float* Wk = (const float*)d_in[7];
    const float* bk = (const float*)d_in[8];
    const float* Wv = (const float*)d_in[9];
    const float* bv = (const float*)d_in[10];
    const float* Wo = (const float*)d_in[11];
    const float* bo = (const float*)d_in[12];

    char* ws = (char*)d_ws;
    int* flag = (int*)ws;
    unsigned short* base = (unsigned short*)(ws + 256);
    const size_t M8 = (size_t)8 * 1024 * 1024;
    unsigned short* Qs  = base;
    unsigned short* Ksb = base + M8;
    unsigned short* Vs  = base + 2 * M8;         // raw V proj; dead after vtrans -> reused for Mb
    unsigned short* Vtb = base + 3 * M8;
    unsigned short* AO  = base + 4 * M8;
    unsigned short* Wt  = base + 5 * M8;
    unsigned short* Abf = base + 5 * M8 + 4 * 1024 * 1024;
    unsigned long long* Mb = (unsigned long long*)Vs;
    const size_t need_abf = 256 + (5 * M8 + 4 * 1024 * 1024 + 3 * M8) * sizeof(unsigned short);
    const bool useAbf = ws_size >= need_abf;

    detect_mask_kernel<<<1, 256, 0, stream>>>((const unsigned int*)mask, flag);
    wconv_kernel<<<dim3(16, 16, 4), 256, 0, stream>>>(Wq, Wk, Wv, Wo, Wt);
    if (useAbf) {
        aconv_kernel<<<dim3(4096, 3), 256, 0, stream>>>(queries, keys, values, Abf);
        gemm_proj8_kernel<<<dim3(32, 4, 3), 512, 131072, stream>>>(Abf, Wt, bq, bk, bv, Qs);
    } else {
        proj_f32_kernel<<<dim3(64, 16, 3), 256, 0, stream>>>(queries, keys, values, Wt, bq, bk, bv, Qs);
    }
    vtrans_kernel<<<dim3(16, 128), 256, 0, stream>>>(Vs, Vtb);
    maskpack_kernel<<<dim3(2048), 256, 0, stream>>>(mask, flag, Mb, 2 * 1024 * 1024);
    attn_kernel<<<dim3(1024), 512, 98304, stream>>>(Qs, Ksb, Vtb, attw, Mb, AO);
    gemm_out_kernel<<<dim3(64, 8), 256, 0, stream>>>(AO, Wt + (size_t)3 * 1024 * 1024, bo, (float*)d_out);
}

// Round 12
// 397.277 us; speedup vs baseline: 1.0762x; 1.0762x over previous
//
#include <hip/hip_runtime.h>
#include <hip/hip_bf16.h>

// ---------- types ----------
using short8 = __attribute__((ext_vector_type(8))) short;
using f32x4  = __attribute__((ext_vector_type(4))) float;

// f32 -> bf16 round-to-nearest-even
__device__ __forceinline__ unsigned short f2bf(float f) {
    union { float f; unsigned u; } x; x.f = f;
    unsigned r = x.u + 0x7FFFu + ((x.u >> 16) & 1u);
    return (unsigned short)(r >> 16);
}

// async global->LDS, 16B per lane; lds base must be wave-uniform
__device__ __forceinline__ void gload_lds16(const void* g, void* l) {
    __builtin_amdgcn_global_load_lds(
        (const __attribute__((address_space(1))) unsigned int*)g,
        (__attribute__((address_space(3))) unsigned int*)l, 16, 0, 0);
}

// ---------- mask dtype detector ----------
__global__ void detect_mask_kernel(const unsigned int* __restrict__ m, int* __restrict__ flag) {
    if (threadIdx.x == 0) *flag = 0;
    __syncthreads();
    unsigned v = m[threadIdx.x];
    if (v > 1u) {
        atomicOr(flag, 1);
        if (v != 0x3F800000u) atomicOr(flag, 2);
    }
}

// ---------- pack mask into bitmask (grid-stride) ----------
__global__ __launch_bounds__(256) void maskpack_kernel(
    const void* __restrict__ mask, const int* __restrict__ flag,
    unsigned long long* __restrict__ Mb, int nwords)
{
    const int l = threadIdx.x & 63;
    const int gwave = (int)((blockIdx.x * 256 + threadIdx.x) >> 6);
    const int nw = (int)((gridDim.x * 256) >> 6);
    const bool bytem = ((*flag) & 2) != 0;
    const unsigned char* m8 = (const unsigned char*)mask;
    const unsigned int* m32 = (const unsigned int*)mask;
    for (int w0 = gwave * 4; w0 < nwords; w0 += nw * 4) {
        unsigned v[4];
#pragma unroll
        for (int u = 0; u < 4; u++) {
            size_t e = (size_t)(w0 + u) * 64 + l;
            v[u] = bytem ? (unsigned)m8[e] : m32[e];
        }
#pragma unroll
        for (int u = 0; u < 4; u++) {
            unsigned long long b = __ballot(v[u] != 0u);
            if (l == 0) Mb[w0 + u] = b;
        }
    }
}

// ---------- transpose-convert W (f32 [k][n]) -> Wt (bf16 [n][k]) ----------
__global__ __launch_bounds__(256) void wconv_kernel(
    const float* __restrict__ W0, const float* __restrict__ W1,
    const float* __restrict__ W2, const float* __restrict__ W3,
    unsigned short* __restrict__ Wt)
{
    const int z = blockIdx.z;
    const float* W = (z == 0) ? W0 : ((z == 1) ? W1 : ((z == 2) ? W2 : W3));
    unsigned short* O = Wt + (size_t)z * 1024 * 1024;
    __shared__ float tile[64][68];
    const int t = threadIdx.x;
    const int k0 = blockIdx.x * 64, n0 = blockIdx.y * 64;
    const int rr = t >> 4, cc = t & 15;
#pragma unroll
    for (int i = 0; i < 4; i++) {
        int row = rr + i * 16;
        float4 v = *reinterpret_cast<const float4*>(W + (size_t)(k0 + row) * 1024 + n0 + cc * 4);
        *reinterpret_cast<float4*>(&tile[row][cc * 4]) = v;
    }
    __syncthreads();
#pragma unroll
    for (int i = 0; i < 4; i++) {
        int rn = rr + i * 16;
        ushort4 ov;
        ov.x = f2bf(tile[cc * 4 + 0][rn]);
        ov.y = f2bf(tile[cc * 4 + 1][rn]);
        ov.z = f2bf(tile[cc * 4 + 2][rn]);
        ov.w = f2bf(tile[cc * 4 + 3][rn]);
        *reinterpret_cast<ushort4*>(O + (size_t)(n0 + rn) * 1024 + k0 + cc * 4) = ov;
    }
}

// ---------- convert f32 A -> bf16 A ----------
__global__ __launch_bounds__(256) void aconv_kernel(
    const float* __restrict__ Aq, const float* __restrict__ Ak, const float* __restrict__ Av,
    unsigned short* __restrict__ Out)
{
    const int z = blockIdx.y;
    const float* A = (z == 0) ? Aq : ((z == 1) ? Ak : Av);
    unsigned short* O = Out + (size_t)z * 8192 * 1024;
    size_t i = ((size_t)blockIdx.x * 256 + threadIdx.x) * 8;
    float4 v0 = *reinterpret_cast<const float4*>(A + i);
    float4 v1 = *reinterpret_cast<const float4*>(A + i + 4);
    short8 o;
    o[0] = (short)f2bf(v0.x); o[1] = (short)f2bf(v0.y);
    o[2] = (short)f2bf(v0.z); o[3] = (short)f2bf(v0.w);
    o[4] = (short)f2bf(v1.x); o[5] = (short)f2bf(v1.y);
    o[6] = (short)f2bf(v1.z); o[7] = (short)f2bf(v1.w);
    *reinterpret_cast<short8*>(O + i) = o;
}

// ================= 256x128 BK=32 GEMM core, 3-buf LDS, stage lead-2, =================
// counted vmcnt(3) at tile end; 2 phases/tile {barrier, lgkmcnt(0), setprio, 8 MFMA}.
// A [M][1024] bf16 rm, W [N][1024] bf16 rm. 512 thr = 8 waves (wm=w>>2 x wn=w&3).
// LDS: A bufs 3x16KB @0, B bufs 3x8KB @49152; total 73728 B -> 2 blocks/CU.
// Swizzle (64B rows): sw(row)=((row>>1)&3)<<4; staged pre-swizzled from source.
#define P8_STAGE(T2, BS)                                                                    \
    gload_lds16(gA0 + (size_t)(T2) * 64, smem + (BS) * 16384 + w * 1024);                   \
    gload_lds16(gA1 + (size_t)(T2) * 64, smem + (BS) * 16384 + 8192 + w * 1024);            \
    gload_lds16(gBp + (size_t)(T2) * 64, smem + 49152 + (BS) * 8192 + w * 1024);

#define P8_TILE(T, BR, BS, DOST, DOW, WN)                                                   \
    {                                                                                       \
        if (DOST) { P8_STAGE((T) + 2, BS) }                                                 \
        short8 a0[4], bb[2], a1[4];                                                         \
        _Pragma("unroll")                                                                   \
        for (int mf = 0; mf < 4; mf++)                                                      \
            a0[mf] = *reinterpret_cast<const short8*>(smem + (BR) * 16384 + ard + mf * 1024); \
        _Pragma("unroll")                                                                   \
        for (int nf = 0; nf < 2; nf++)                                                      \
            bb[nf] = *reinterpret_cast<const short8*>(smem + 49152 + (BR) * 8192 + brd + nf * 1024); \
        __builtin_amdgcn_s_barrier();                                                       \
        asm volatile("s_waitcnt lgkmcnt(0)" ::: "memory");                                  \
        __builtin_amdgcn_sched_barrier(0);                                                  \
        __builtin_amdgcn_s_setprio(1);                                                      \
        _Pragma("unroll")                                                                   \
        for (int mf = 0; mf < 4; mf++)                                                      \
            _Pragma("unroll")                                                               \
            for (int nf = 0; nf < 2; nf++)                                                  \
                acc[mf][nf] = __builtin_amdgcn_mfma_f32_16x16x32_bf16(a0[mf], bb[nf], acc[mf][nf], 0, 0, 0); \
        __builtin_amdgcn_s_setprio(0);                                                      \
        _Pragma("unroll")                                                                   \
        for (int mf = 0; mf < 4; mf++)                                                      \
            a1[mf] = *reinterpret_cast<const short8*>(smem + (BR) * 16384 + 4096 + ard + mf * 1024); \
        __builtin_amdgcn_s_barrier();                                                       \
        asm volatile("s_waitcnt lgkmcnt(0)" ::: "memory");                                  \
        __builtin_amdgcn_sched_barrier(0);                                                  \
        __builtin_amdgcn_s_setprio(1);                                                      \
        _Pragma("unroll")                                                                   \
        for (int mf = 0; mf < 4; mf++)                                                      \
            _Pragma("unroll")                                                               \
            for (int nf = 0; nf < 2; nf++)                                                  \
                acc[4 + mf][nf] = __builtin_amdgcn_mfma_f32_16x16x32_bf16(a1[mf], bb[nf], acc[4 + mf][nf], 0, 0, 0); \
        __builtin_amdgcn_s_setprio(0);                                                      \
        if (DOW) { asm volatile("s_waitcnt vmcnt(" #WN ")" ::: "memory"); }                 \
        __builtin_amdgcn_s_barrier();                                                       \
        __builtin_amdgcn_sched_barrier(0);                                                  \
    }

#define GEMM8_CORE(A_PTR, W_PTR)                                                            \
    extern __shared__ char smem[];                                                          \
    const int tid = threadIdx.x, w = tid >> 6, l = tid & 63, l16 = l & 15, g = l >> 4;      \
    const int wm = w >> 2, wn = w & 3;                                                      \
    const int row0 = blockIdx.x * 256, col0 = blockIdx.y * 128;                             \
    const int csrc = ((l & 3) * 16) ^ (((l >> 3) & 3) << 4);                                \
    const char* gA0 = (const char*)(A_PTR) + (size_t)(row0 + w * 16 + (l >> 2)) * 2048 + csrc; \
    const char* gA1 = gA0 + (size_t)128 * 2048;                                             \
    const char* gBp = (const char*)(W_PTR) + (size_t)(col0 + w * 16 + (l >> 2)) * 2048 + csrc; \
    const int sw = ((l16 >> 1) & 3) << 4;                                                   \
    const int ard = (wm * 128 + l16) * 64 + ((g * 16) ^ sw);                                \
    const int brd = (wn * 32 + l16) * 64 + ((g * 16) ^ sw);                                 \
    f32x4 acc[8][2];                                                                        \
    _Pragma("unroll")                                                                       \
    for (int i = 0; i < 8; i++)                                                             \
        _Pragma("unroll")                                                                   \
        for (int j = 0; j < 2; j++) acc[i][j] = (f32x4){0.f, 0.f, 0.f, 0.f};                \
    P8_STAGE(0, 0)                                                                          \
    P8_STAGE(1, 1)                                                                          \
    asm volatile("s_waitcnt vmcnt(3)" ::: "memory");                                        \
    __builtin_amdgcn_s_barrier();                                                           \
    __builtin_amdgcn_sched_barrier(0);                                                      \
    for (int tb = 0; tb < 30; tb += 3) {                                                    \
        P8_TILE(tb + 0, 0, 2, 1, 1, 3)                                                      \
        P8_TILE(tb + 1, 1, 0, 1, 1, 3)                                                      \
        P8_TILE(tb + 2, 2, 1, 1, 1, 3)                                                      \
    }                                                                                       \
    P8_TILE(30, 0, 0, 0, 1, 0)                                                              \
    P8_TILE(31, 1, 0, 0, 0, 0)

// ---------- projections: Out_z = A_z @ W_z^T + b_z -> bf16 [b][h][n][64] ----------
__global__ __launch_bounds__(512, 4) void gemm_proj8_kernel(
    const unsigned short* __restrict__ Abf,  // [3][8192][1024]
    const unsigned short* __restrict__ Wt,   // [3][1024 n][1024 k]
    const float* __restrict__ bq, const float* __restrict__ bk, const float* __restrict__ bv,
    unsigned short* __restrict__ Out)        // [3][8][16][1024][64]
{
    const int z = blockIdx.z;
    const unsigned short* A = Abf + (size_t)z * 8192 * 1024;
    const unsigned short* Wz = Wt + (size_t)z * 1024 * 1024;
    const float* bias = (z == 0) ? bq : ((z == 1) ? bk : bv);
    unsigned short* Oz = Out + (size_t)z * 8 * 16 * 1024 * 64;

    GEMM8_CORE(A, Wz)

#pragma unroll
    for (int mf8 = 0; mf8 < 8; mf8++)
#pragma unroll
        for (int nf = 0; nf < 2; nf++)
#pragma unroll
            for (int r = 0; r < 4; r++) {
                int row = row0 + wm * 128 + mf8 * 16 + g * 4 + r;
                int col = col0 + wn * 32 + nf * 16 + l16;
                float val = acc[mf8][nf][r] + bias[col];
                int bb = row >> 10, n = row & 1023;
                int hh = col >> 6, d = col & 63;
                Oz[(((size_t)(bb * 16 + hh)) * 1024 + n) * 64 + d] = f2bf(val);
            }
}

// ---------- output projection: d_out = AO @ Wo^T + bo (f32 out) ----------
__global__ __launch_bounds__(512, 4) void gemm_out8_kernel(
    const unsigned short* __restrict__ Ain,  // [8192][1024] bf16
    const unsigned short* __restrict__ Wto,  // [1024 n][1024 k] bf16
    const float* __restrict__ bo,
    float* __restrict__ Out)                 // [8192][1024] f32
{
    GEMM8_CORE(Ain, Wto)

#pragma unroll
    for (int mf8 = 0; mf8 < 8; mf8++)
#pragma unroll
        for (int nf = 0; nf < 2; nf++)
#pragma unroll
            for (int r = 0; r < 4; r++) {
                int row = row0 + wm * 128 + mf8 * 16 + g * 4 + r;
                int col = col0 + wn * 32 + nf * 16 + l16;
                Out[(size_t)row * 1024 + col] = acc[mf8][nf][r] + bo[col];
            }
}

// ---------- projection GEMM (f32 A fallback, converts in-loop) ----------
__global__ __launch_bounds__(256) void proj_f32_kernel(
    const float* __restrict__ Aq, const float* __restrict__ Ak, const float* __restrict__ Av,
    const unsigned short* __restrict__ Wt,
    const float* __restrict__ bq, const float* __restrict__ bk, const float* __restrict__ bv,
    unsigned short* __restrict__ Out)
{
    const int z = blockIdx.z;
    const float* A = (z == 0) ? Aq : ((z == 1) ? Ak : Av);
    const float* bias = (z == 0) ? bq : ((z == 1) ? bk : bv);
    const unsigned short* Wz = Wt + (size_t)z * 1024 * 1024;
    unsigned short* Oz = Out + (size_t)z * 8 * 16 * 1024 * 64;

    const int tid = threadIdx.x;
    const int w = tid >> 6, l = tid & 63;
    const int l16 = l & 15, g = l >> 4;
    const int rbase = blockIdx.x * 128 + w * 32;
    const int cbase = blockIdx.y * 64;

    f32x4 acc[2][4];
#pragma unroll
    for (int i = 0; i < 2; i++)
#pragma unroll
        for (int j = 0; j < 4; j++) acc[i][j] = (f32x4){0.f, 0.f, 0.f, 0.f};

#pragma unroll 2
    for (int k0 = 0; k0 < 1024; k0 += 32) {
        short8 a[2];
#pragma unroll
        for (int rf = 0; rf < 2; rf++) {
            const float* ap = A + (size_t)(rbase + rf * 16 + l16) * 1024 + k0 + g * 8;
            float4 v0 = *reinterpret_cast<const float4*>(ap);
            float4 v1 = *reinterpret_cast<const float4*>(ap + 4);
            short8 av;
            av[0] = (short)f2bf(v0.x); av[1] = (short)f2bf(v0.y);
            av[2] = (short)f2bf(v0.z); av[3] = (short)f2bf(v0.w);
            av[4] = (short)f2bf(v1.x); av[5] = (short)f2bf(v1.y);
            av[6] = (short)f2bf(v1.z); av[7] = (short)f2bf(v1.w);
            a[rf] = av;
        }
        short8 bfr[4];
#pragma unroll
        for (int cf = 0; cf < 4; cf++)
            bfr[cf] = *reinterpret_cast<const short8*>(Wz + (size_t)(cbase + cf * 16 + l16) * 1024 + k0 + g * 8);
#pragma unroll
        for (int rf = 0; rf < 2; rf++)
#pragma unroll
            for (int cf = 0; cf < 4; cf++)
                acc[rf][cf] = __builtin_amdgcn_mfma_f32_16x16x32_bf16(a[rf], bfr[cf], acc[rf][cf], 0, 0, 0);
    }

#pragma unroll
    for (int rf = 0; rf < 2; rf++)
#pragma unroll
        for (int cf = 0; cf < 4; cf++)
#pragma unroll
            for (int r = 0; r < 4; r++) {
                int row = rbase + rf * 16 + g * 4 + r;
                int col = cbase + cf * 16 + l16;
                float val = acc[rf][cf][r] + bias[col];
                int bb = row >> 10, n = row & 1023;
                int h = col >> 6, d = col & 63;
                Oz[(((size_t)(bb * 16 + h)) * 1024 + n) * 64 + d] = f2bf(val);
            }
}

// ---------- transpose V: Vs [bh][k][64 d] -> Vt [bh][64 d][1024 k] ----------
__global__ __launch_bounds__(256) void vtrans_kernel(
    const unsigned short* __restrict__ Vs, unsigned short* __restrict__ Vt)
{
    const int bh = blockIdx.y;
    const int k0 = blockIdx.x * 64;
    const unsigned short* In = Vs + (size_t)bh * 1024 * 64;
    unsigned short* O = Vt + (size_t)bh * 64 * 1024;
    __shared__ unsigned short tile[64][72];
    const int t = threadIdx.x;
    {
        const int row = t >> 3;
        const int c8 = (t & 7) * 8;
#pragma unroll
        for (int i = 0; i < 2; i++) {
            int r = row + i * 32;
            short8 v = *reinterpret_cast<const short8*>(In + (size_t)(k0 + r) * 64 + c8);
            *reinterpret_cast<short8*>(&tile[r][c8]) = v;
        }
    }
    __syncthreads();
    {
        const int rd = t >> 4, c4 = (t & 15) * 4;
#pragma unroll
        for (int i = 0; i < 4; i++) {
            int d = rd + i * 16;
            ushort4 ov;
            ov.x = tile[c4 + 0][d];
            ov.y = tile[c4 + 1][d];
            ov.z = tile[c4 + 2][d];
            ov.w = tile[c4 + 3][d];
            *reinterpret_cast<ushort4*>(O + (size_t)d * 1024 + k0 + c4) = ov;
        }
    }
}

// ---------- fused attention, KVBLK=128 (unchanged from round 10) ----------
__global__ __launch_bounds__(512, 1) void attn_kernel(
    const unsigned short* __restrict__ Qs,     // [bh][1024][64]
    const unsigned short* __restrict__ Ks,     // [bh][1024][64]
    const unsigned short* __restrict__ Vt,     // [bh][64 d][1024 k]
    const float* __restrict__ attw,            // [bh][1024][1024]
    const unsigned long long* __restrict__ Mb, // [bh*1024 rows][16 words]
    unsigned short* __restrict__ AO)           // [b][q][h*64+d] bf16
{
    extern __shared__ char smem[];

    const int bid = blockIdx.x;
    const int xj = bid & 7, xp = bid >> 3;
    const int qt = xp & 7;
    const int gbh = (xp >> 3) * 8 + xj;
    const int h = gbh & 15, b = gbh >> 4;
    const int bh = b * 16 + h;

    const int tid = threadIdx.x, w = tid >> 6, l = tid & 63, l16 = l & 15, g = l >> 4;
    const int myq = qt * 128 + w * 16 + l16;

    const unsigned short* Qbh = Qs + (size_t)bh * 65536;
    const char* Kb = (const char*)(Ks + (size_t)bh * 65536);
    const char* Vb = (const char*)(Vt + (size_t)bh * 65536);
    const float* wrow = attw + ((size_t)bh * 1024 + myq) * 1024;
    const unsigned long long* mrow = Mb + ((size_t)bh * 1024 + myq) * 16;

    const int kb_swz = ((l & 7) * 16) ^ ((l >> 3) << 4);
    const char* gKb = Kb + (size_t)(w * 16 + (l >> 3)) * 128 + kb_swz;
    const int vrow0 = w * 8 + (l >> 4);
    const char* gVb0 = Vb + (size_t)vrow0 * 2048 + (((l & 15) * 16) ^ ((vrow0 & 7) << 4));
    const char* gVb1 = Vb + (size_t)(vrow0 + 4) * 2048 + (((l & 15) * 16) ^ (((vrow0 + 4) & 7) << 4));

    const int swz = (l16 & 7) << 4;
    const int krdA = l16 * 128 + ((g * 16) ^ swz);
    const int krdB = l16 * 128 + ((64 + g * 16) ^ swz);
    char* const pbase = smem + 65536 + w * 4096 + l16 * 256;

    gload_lds16(gKb, smem + w * 2048);
    gload_lds16(gKb + 1024, smem + w * 2048 + 1024);
    gload_lds16(gVb0, smem + 32768 + w * 2048);
    gload_lds16(gVb1, smem + 32768 + w * 2048 + 1024);
    __builtin_amdgcn_sched_barrier(0);

    short8 qf0 = *reinterpret_cast<const short8*>(Qbh + (size_t)myq * 64 + g * 8);
    short8 qf1 = *reinterpret_cast<const short8*>(Qbh + (size_t)myq * 64 + 32 + g * 8);
    float4 wv[8];
    unsigned long long mb0, mb1;
#pragma unroll
    for (int cf = 0; cf < 8; cf++)
        wv[cf] = *reinterpret_cast<const float4*>(wrow + cf * 16 + g * 4);
    mb0 = mrow[0];
    mb1 = mrow[1];

    asm volatile("s_waitcnt vmcnt(12)" ::: "memory");
    __builtin_amdgcn_s_barrier();
    __builtin_amdgcn_sched_barrier(0);

    f32x4 accO[4];
#pragma unroll
    for (int j = 0; j < 4; j++) accO[j] = (f32x4){0.f, 0.f, 0.f, 0.f};
    float den = 0.f;

#define ATTN_BODY(CURK)                                                                     \
    _Pragma("unroll")                                                                       \
    for (int cf = 0; cf < 8; cf++) {                                                        \
        short8 k0 = *reinterpret_cast<const short8*>(smem + (CURK) + krdA + cf * 2048);     \
        short8 k1 = *reinterpret_cast<const short8*>(smem + (CURK) + krdB + cf * 2048);     \
        f32x4 s = (f32x4){0.f, 0.f, 0.f, 0.f};                                              \
        s = __builtin_amdgcn_mfma_f32_16x16x32_bf16(k0, qf0, s, 0, 0, 0);                   \
        s = __builtin_amdgcn_mfma_f32_16x16x32_bf16(k1, qf1, s, 0, 0, 0);                   \
        unsigned mn = (unsigned)((cf < 4 ? mb0 >> (cf * 16 + g * 4)                         \
                                         : mb1 >> ((cf - 4) * 16 + g * 4))) & 0xFu;         \
        float p0 = (mn & 1u) ? 0.f : __expf(s[0] * 0.125f * wv[cf].x);                      \
        float p1 = (mn & 2u) ? 0.f : __expf(s[1] * 0.125f * wv[cf].y);                      \
        float p2 = (mn & 4u) ? 0.f : __expf(s[2] * 0.125f * wv[cf].z);                      \
        float p3 = (mn & 8u) ? 0.f : __expf(s[3] * 0.125f * wv[cf].w);                      \
        den += p0 + p1 + p2 + p3;                                                           \
        ushort4 pwv;                                                                        \
        pwv.x = f2bf(p0); pwv.y = f2bf(p1); pwv.z = f2bf(p2); pwv.w = f2bf(p3);             \
        *reinterpret_cast<ushort4*>(pbase + ((cf * 32 + g * 8) ^ swz)) = pwv;               \
    }

#define ATTN_PV(CURV)                                                                       \
    _Pragma("unroll")                                                                       \
    for (int ks = 0; ks < 4; ks++) {                                                        \
        short8 pf = *reinterpret_cast<const short8*>(pbase + ((ks * 64 + g * 16) ^ swz));   \
        _Pragma("unroll")                                                                   \
        for (int cd = 0; cd < 4; cd++) {                                                    \
            short8 vf = *reinterpret_cast<const short8*>(                                   \
                smem + 32768 + (CURV) + (cd * 16 + l16) * 256 + ((ks * 64 + g * 16) ^ swz));\
            accO[cd] = __builtin_amdgcn_mfma_f32_16x16x32_bf16(pf, vf, accO[cd], 0, 0, 0);  \
        }                                                                                   \
    }

    for (int t = 0; t < 7; t++) {
        const int cur = (t & 1) * 16384, nxt = 16384 - cur;
        gload_lds16(gKb + (size_t)(t + 1) * 16384, smem + nxt + w * 2048);
        gload_lds16(gKb + (size_t)(t + 1) * 16384 + 1024, smem + nxt + w * 2048 + 1024);
        gload_lds16(gVb0 + (size_t)(t + 1) * 256, smem + 32768 + nxt + w * 2048);
        gload_lds16(gVb1 + (size_t)(t + 1) * 256, smem + 32768 + nxt + w * 2048 + 1024);
        __builtin_amdgcn_sched_barrier(0);

        ATTN_BODY(cur)

#pragma unroll
        for (int cf = 0; cf < 8; cf++)
            wv[cf] = *reinterpret_cast<const float4*>(wrow + (t + 1) * 128 + cf * 16 + g * 4);
        mb0 = mrow[2 * (t + 1)];
        mb1 = mrow[2 * (t + 1) + 1];

        ATTN_PV(cur)

        asm volatile("s_waitcnt vmcnt(10)" ::: "memory");
        __builtin_amdgcn_s_barrier();
        __builtin_amdgcn_sched_barrier(0);
    }
    ATTN_BODY(16384)
    ATTN_PV(16384)
#undef ATTN_BODY
#undef ATTN_PV

    den += __shfl_xor(den, 16);
    den += __shfl_xor(den, 32);

#pragma unroll
    for (int r = 0; r < 4; r++) {
        float dr = __shfl(den, g * 4 + r);
        float inv = 1.0f / dr;
#pragma unroll
        for (int cd = 0; cd < 4; cd++) {
            int qrow = qt * 128 + w * 16 + g * 4 + r;
            int col = h * 64 + cd * 16 + l16;
            AO[((size_t)b * 1024 + qrow) * 1024 + col] = f2bf(accO[cd][r] * inv);
        }
    }
}

extern "C" void kernel_launch(void* const* d_in, const int* in_sizes, int n_in,
                              void* d_out, int out_size, void* d_ws, size_t ws_size,
                              hipStream_t stream)
{
    const float* queries = (const float*)d_in[0];
    const float* keys    = (const float*)d_in[1];
    const float* values  = (const float*)d_in[2];
    const void*  mask    = d_in[3];
    const float* attw    = (const float*)d_in[4];
    const float* Wq = (const float*)d_in[5];
    const float* bq = (const float*)d_in[6];
    const float* Wk = (const float*)d_in[7];
    const float* bk = (const float*)d_in[8];
    const float* Wv = (const float*)d_in[9];
    const float* bv = (const float*)d_in[10];
    const float* Wo = (const float*)d_in[11];
    const float* bo = (const float*)d_in[12];

    char* ws = (char*)d_ws;
    int* flag = (int*)ws;
    unsigned short* base = (unsigned short*)(ws + 256);
    const size_t M8 = (size_t)8 * 1024 * 1024;
    unsigned short* Qs  = base;
    unsigned short* Ksb = base + M8;
    unsigned short* Vs  = base + 2 * M8;         // raw V proj; dead after vtrans -> reused for Mb
    unsigned short* Vtb = base + 3 * M8;
    unsigned short* AO  = base + 4 * M8;
    unsigned short* Wt  = base + 5 * M8;
    unsigned short* Abf = base + 5 * M8 + 4 * 1024 * 1024;
    unsigned long long* Mb = (unsigned long long*)Vs;
    const size_t need_abf = 256 + (5 * M8 + 4 * 1024 * 1024 + 3 * M8) * sizeof(unsigned short);
    const bool useAbf = ws_size >= need_abf;

    detect_mask_kernel<<<1, 256, 0, stream>>>((const unsigned int*)mask, flag);
    wconv_kernel<<<dim3(16, 16, 4), 256, 0, stream>>>(Wq, Wk, Wv, Wo, Wt);
    if (useAbf) {
        aconv_kernel<<<dim3(4096, 3), 256, 0, stream>>>(queries, keys, values, Abf);
        gemm_proj8_kernel<<<dim3(32, 8, 3), 512, 73728, stream>>>(Abf, Wt, bq, bk, bv, Qs);
    } else {
        proj_f32_kernel<<<dim3(64, 16, 3), 256, 0, stream>>>(queries, keys, values, Wt, bq, bk, bv, Qs);
    }
    vtrans_kernel<<<dim3(16, 128), 256, 0, stream>>>(Vs, Vtb);
    maskpack_kernel<<<dim3(2048), 256, 0, stream>>>(mask, flag, Mb, 2 * 1024 * 1024);
    attn_kernel<<<dim3(1024), 512, 98304, stream>>>(Qs, Ksb, Vtb, attw, Mb, AO);
    gemm_out8_kernel<<<dim3(32, 8), 512, 73728, stream>>>(AO, Wt + (size_t)3 * 1024 * 1024, bo, (float*)d_out);
}